// Round 18
// baseline (49.797 us; speedup 1.0000x reference)
//
#include <hip/hip_runtime.h>
#include <math.h>

#define N_   16
#define L_   512
#define C_   256
#define T_   4096
#define EPSL 1e-5f
#define BM   32           // dur rows per block

typedef float f32x4 __attribute__((ext_vector_type(4)));
typedef long  long2v __attribute__((ext_vector_type(2)));

// HW packed fp32 -> fp8 e4m3 (OCP on gfx950): 2 floats -> bytes {lo,hi} of
// one 16-bit half-word of dst; HI selects which half-word (must be literal).
template<bool HI>
__device__ __forceinline__ unsigned cvt2(float a, float b, unsigned old) {
    return (unsigned)__builtin_amdgcn_cvt_pk_fp8_f32(a, b, (int)old, HI);
}

// ---------------------------------------------------------------------------
// pack BOTH conv weights into fp8 MFMA B-fragment-PAIR order + write WVF_pos:
//   bpk[karm][cg(16)][fp(4)][lane(64)][16B] where bytes 0-7 = k-slice s=2fp,
//   bytes 8-15 = s=2fp+1;  byte e of slice s =
//   fp8(w[karm][cin = s*32 + (lane>>4)*8 + e][cout = cg*16 + (lane&15)])
// ---------------------------------------------------------------------------
__global__ __launch_bounds__(256) void pack_w_kernel(
    const float* __restrict__ w1, const float* __restrict__ w2,
    unsigned char* __restrict__ bpk1, unsigned char* __restrict__ bpk2,
    float* __restrict__ wpos)
{
    int gid = blockIdx.x * 256 + threadIdx.x;        // 24576 total (96 blocks)
    if (gid < T_) wpos[gid] = (float)(gid + 1);
    const float* w      = (gid < 12288) ? w1 : w2;
    unsigned char* bpk  = (gid < 12288) ? bpk1 : bpk2;
    int g2 = gid & 12287;
    int lane = g2 & 63;
    int fp   = (g2 >> 6) & 3;
    int cg   = (g2 >> 8) & 15;
    int karm = g2 >> 12;                             // 0..2
    int cout = cg * 16 + (lane & 15);
    int cin0 = (2 * fp) * 32 + (lane >> 4) * 8;      // slice s = 2fp
    const float* s0 = w + (size_t)(karm * 256 + cin0) * 256 + cout;
    const float* s1 = s0 + (size_t)32 * 256;         // slice s = 2fp+1
    float v0[8], v1[8];
    #pragma unroll
    for (int e = 0; e < 8; ++e) {
        v0[e] = s0[(size_t)e * 256];
        v1[e] = s1[(size_t)e * 256];
    }
    unsigned a0 = cvt2<false>(v0[0], v0[1], 0); a0 = cvt2<true>(v0[2], v0[3], a0);
    unsigned a1 = cvt2<false>(v0[4], v0[5], 0); a1 = cvt2<true>(v0[6], v0[7], a1);
    unsigned b0 = cvt2<false>(v1[0], v1[1], 0); b0 = cvt2<true>(v1[2], v1[3], b0);
    unsigned b1 = cvt2<false>(v1[4], v1[5], 0); b1 = cvt2<true>(v1[6], v1[7], b1);
    uint4* dst = reinterpret_cast<uint4*>(bpk + (size_t)g2 * 16);
    *dst = make_uint4(a0, a1, b0, b1);
}

// ---- B prefetch: 2 col-groups x 8 k-slices via 8 dwordx4 loads ----
#define LDB(BPK, KARM, DST) do {                                              \
    const unsigned char* bb_ = (BPK) + ((size_t)((KARM) * 16 + cg0)) * 4096 + lane * 16; \
    _Pragma("unroll")                                                         \
    for (int f_ = 0; f_ < 4; ++f_) {                                          \
        long2v v0_ = *reinterpret_cast<const long2v*>(bb_ + f_ * 1024);       \
        long2v v1_ = *reinterpret_cast<const long2v*>(bb_ + 4096 + f_ * 1024);\
        DST[2*f_]     = v0_[0];  DST[2*f_ + 1]     = v0_[1];                  \
        DST[8 + 2*f_] = v1_[0];  DST[8 + 2*f_ + 1] = v1_[1];                  \
    } } while (0)

// A-fragment LDS byte offset (fp8): row RA, k-slice S, k-group lg.
#define AOFF(BUF, RA, S)                                                      \
    (BUF + (RA) * 256 + (((((S) << 1) + (lg >> 1)) ^ ((RA) & 15)) << 4) + ((lg & 1) << 3))

// ---- one karm of conv1: 3 row-tiles x 2 col-groups = 48 MFMAs ----
#define CONV1K(KARM, B) do {                                                  \
    _Pragma("unroll")                                                         \
    for (int s_ = 0; s_ < 8; ++s_) {                                          \
        _Pragma("unroll")                                                     \
        for (int t_ = 0; t_ < 3; ++t_) {                                      \
            int rA_ = 16 * t_ + lr + (KARM);                                  \
            long a_ = *reinterpret_cast<const long*>(AOFF(xt, rA_, s_));      \
            acc1[t_][0] = __builtin_amdgcn_mfma_f32_16x16x32_fp8_fp8(a_, B[s_],     acc1[t_][0], 0, 0, 0); \
            acc1[t_][1] = __builtin_amdgcn_mfma_f32_16x16x32_fp8_fp8(a_, B[8 + s_], acc1[t_][1], 0, 0, 0); \
        } } } while (0)

// ---- one karm of conv2: 2 row-tiles x 2 col-groups = 32 MFMAs ----
#define CONV2K(KARM, B) do {                                                  \
    _Pragma("unroll")                                                         \
    for (int s_ = 0; s_ < 8; ++s_) {                                          \
        _Pragma("unroll")                                                     \
        for (int t_ = 0; t_ < 2; ++t_) {                                      \
            int rA_ = 16 * t_ + lr + (KARM);                                  \
            long a_ = *reinterpret_cast<const long*>(AOFF(h1t, rA_, s_));     \
            c2[t_][0] = __builtin_amdgcn_mfma_f32_16x16x32_fp8_fp8(a_, B[s_],     c2[t_][0], 0, 0, 0); \
            c2[t_][1] = __builtin_amdgcn_mfma_f32_16x16x32_fp8_fp8(a_, B[8 + s_], c2[t_][1], 0, 0, 0); \
        } } } while (0)

// ---------------------------------------------------------------------------
// FUSED conv1+LN+ReLU -> conv2+LN+ReLU+linear -> dur, fp8 MFMA, HW fp8 cvt.
// Identical to R16 (measured: 12.9 us in graph-replay conditions).
// ---------------------------------------------------------------------------
__global__ __launch_bounds__(512) void fused_conv_kernel(
    const float* __restrict__ x,
    const unsigned char* __restrict__ bpk1, const unsigned char* __restrict__ bpk2,
    const float* __restrict__ b1, const float* __restrict__ g1, const float* __restrict__ be1,
    const float* __restrict__ b2, const float* __restrict__ g2, const float* __restrict__ be2,
    const float* __restrict__ lw, const float* __restrict__ lb,
    int* __restrict__ dur)
{
    __shared__ __align__(16) char xt[50 * 256];      // fp8 rows l0-2 .. (36 staged)
    __shared__ __align__(16) char h1t[34 * 256];     // fp8 h1 rows l0-1 .. l0+32
    __shared__ float redS[8][48], redQ[8][48], redP[8][32];

    const int tid  = threadIdx.x;
    const int wv   = tid >> 6;                       // 0..7
    const int lane = tid & 63;
    const int lg   = lane >> 4;
    const int lr   = lane & 15;
    const int n    = blockIdx.x >> 4;
    const int l0   = (blockIdx.x & 15) << 5;
    const int cg0  = wv * 2;
    const int col0 = wv * 32 + lr, col1 = col0 + 16;

    long Ba[16], Bb[16], Bc[16];
    LDB(bpk1, 0, Ba);                                // in flight during stage
    LDB(bpk1, 1, Bb);

    // ---- stage x rows l0-2 .. l0+33 (36 rows), f32 -> fp8 (HW cvt) ----
    for (int idx = tid; idx < 36 * 16; idx += 512) { // 16B chunk = 16 cols
        int r = idx >> 4, slot = idx & 15;
        int l = l0 - 2 + r;
        unsigned pk[4] = {0, 0, 0, 0};
        if (l >= 0 && l < L_) {
            const float* src = x + (((size_t)(n * L_ + l)) << 8) + (slot << 4);
            #pragma unroll
            for (int q = 0; q < 4; ++q) {
                f32x4 f = *reinterpret_cast<const f32x4*>(src + q * 4);
                unsigned v = cvt2<false>(f[0], f[1], 0);
                pk[q] = cvt2<true>(f[2], f[3], v);
            }
        }
        *reinterpret_cast<uint4*>(xt + r * 256 + ((slot ^ (r & 15)) << 4)) =
            make_uint4(pk[0], pk[1], pk[2], pk[3]);
    }
    __syncthreads();

    // ---- conv1: 2-deep pipelined karm loop ----
    f32x4 acc1[3][2] = {};
    LDB(bpk1, 2, Bc);  CONV1K(0, Ba);
    LDB(bpk2, 0, Ba);  CONV1K(1, Bb);
    LDB(bpk2, 1, Bb);  CONV1K(2, Bc);
    LDB(bpk2, 2, Bc);                                // lands during epilogue

    // ---- conv1 stats: shfl over 16 cols x 2cg, LDS combine over 8 waves ----
    const float cb10 = b1[col0], cb11 = b1[col1];
    const float cg10 = g1[col0], cg11 = g1[col1];
    const float ce10 = be1[col0], ce11 = be1[col1];
    {
        float sv[12], qv[12];
        #pragma unroll
        for (int t = 0; t < 3; ++t)
            #pragma unroll
            for (int j = 0; j < 4; ++j) {
                float h0 = acc1[t][0][j] + cb10, h1 = acc1[t][1][j] + cb11;
                sv[t*4+j] = h0 + h1; qv[t*4+j] = h0 * h0 + h1 * h1;
            }
        #pragma unroll
        for (int m = 1; m < 16; m <<= 1)
            #pragma unroll
            for (int k = 0; k < 12; ++k) {
                sv[k] += __shfl_xor(sv[k], m, 64);
                qv[k] += __shfl_xor(qv[k], m, 64);
            }
        if (lr == 0) {
            #pragma unroll
            for (int t = 0; t < 3; ++t)
                #pragma unroll
                for (int j = 0; j < 4; ++j) {
                    redS[wv][16*t + lg*4 + j] = sv[t*4+j];
                    redQ[wv][16*t + lg*4 + j] = qv[t*4+j];
                }
        }
    }
    __syncthreads();
    if (tid < 48) {
        float ss = 0.f, qq = 0.f;
        #pragma unroll
        for (int u = 0; u < 8; ++u) { ss += redS[u][tid]; qq += redQ[u][tid]; }
        float m_  = ss * (1.f / 256.f);
        float var = fmaxf(qq * (1.f / 256.f) - m_ * m_, 0.f);
        redS[0][tid] = m_;
        redQ[0][tid] = 1.0f / sqrtf(var + EPSL);
    }
    __syncthreads();

    // ---- normalize + ReLU -> h1t fp8 (rows 0..33 kept, HW cvt) ----
    #pragma unroll
    for (int t = 0; t < 3; ++t)
        #pragma unroll
        for (int j = 0; j < 4; ++j) {
            int hr = 16*t + lg*4 + j;
            if (hr < 34) {
                int hl = l0 - 1 + hr;
                float r0 = 0.f, r1 = 0.f;
                if (hl >= 0 && hl < L_) {
                    r0 = fmaxf((acc1[t][0][j] + cb10 - redS[0][hr]) * redQ[0][hr] * cg10 + ce10, 0.f);
                    r1 = fmaxf((acc1[t][1][j] + cb11 - redS[0][hr]) * redQ[0][hr] * cg11 + ce11, 0.f);
                }
                unsigned pr = cvt2<false>(r0, r1, 0);
                *(unsigned char*)(h1t + hr*256 + (((col0 >> 4) ^ (hr & 15)) << 4) + (col0 & 15)) =
                    (unsigned char)(pr & 0xff);
                *(unsigned char*)(h1t + hr*256 + (((col1 >> 4) ^ (hr & 15)) << 4) + (col1 & 15)) =
                    (unsigned char)((pr >> 8) & 0xff);
            }
        }
    __syncthreads();

    // ---- conv2: all three B buffers already resident ----
    f32x4 c2[2][2] = {};
    CONV2K(0, Ba);
    CONV2K(1, Bb);
    CONV2K(2, Bc);

    // ---- conv2 stats ----
    const float cb20 = b2[col0], cb21 = b2[col1];
    const float cg20 = g2[col0], cg21 = g2[col1];
    const float ce20 = be2[col0], ce21 = be2[col1];
    const float lw0  = lw[col0],  lw1  = lw[col1];
    {
        float sv[8], qv[8];
        #pragma unroll
        for (int tt = 0; tt < 2; ++tt)
            #pragma unroll
            for (int j = 0; j < 4; ++j) {
                float h0 = c2[tt][0][j] + cb20, h1 = c2[tt][1][j] + cb21;
                sv[tt*4+j] = h0 + h1; qv[tt*4+j] = h0 * h0 + h1 * h1;
            }
        #pragma unroll
        for (int m = 1; m < 16; m <<= 1)
            #pragma unroll
            for (int k = 0; k < 8; ++k) {
                sv[k] += __shfl_xor(sv[k], m, 64);
                qv[k] += __shfl_xor(qv[k], m, 64);
            }
        if (lr == 0) {
            #pragma unroll
            for (int tt = 0; tt < 2; ++tt)
                #pragma unroll
                for (int j = 0; j < 4; ++j) {
                    redS[wv][16*tt + lg*4 + j] = sv[tt*4+j];
                    redQ[wv][16*tt + lg*4 + j] = qv[tt*4+j];
                }
        }
    }
    __syncthreads();
    if (tid < 32) {
        float ss = 0.f, qq = 0.f;
        #pragma unroll
        for (int u = 0; u < 8; ++u) { ss += redS[u][tid]; qq += redQ[u][tid]; }
        float m_  = ss * (1.f / 256.f);
        float var = fmaxf(qq * (1.f / 256.f) - m_ * m_, 0.f);
        redS[0][tid] = m_;
        redQ[0][tid] = 1.0f / sqrtf(var + EPSL);
    }
    __syncthreads();

    // ---- LN + ReLU + dot(lw) -> dur ----
    {
        float pv[8];
        #pragma unroll
        for (int tt = 0; tt < 2; ++tt)
            #pragma unroll
            for (int j = 0; j < 4; ++j) {
                int r = 16*tt + lg*4 + j;
                float r0 = fmaxf((c2[tt][0][j] + cb20 - redS[0][r]) * redQ[0][r] * cg20 + ce20, 0.f);
                float r1 = fmaxf((c2[tt][1][j] + cb21 - redS[0][r]) * redQ[0][r] * cg21 + ce21, 0.f);
                pv[tt*4+j] = r0 * lw0 + r1 * lw1;
            }
        #pragma unroll
        for (int m = 1; m < 16; m <<= 1)
            #pragma unroll
            for (int k = 0; k < 8; ++k)
                pv[k] += __shfl_xor(pv[k], m, 64);
        if (lr == 0) {
            #pragma unroll
            for (int tt = 0; tt < 2; ++tt)
                #pragma unroll
                for (int j = 0; j < 4; ++j)
                    redP[wv][16*tt + lg*4 + j] = pv[tt*4+j];
        }
    }
    __syncthreads();
    if (tid < 32) {
        float dot = lb[0];
        #pragma unroll
        for (int u = 0; u < 8; ++u) dot += redP[u][tid];
        dur[n * L_ + l0 + tid] = (int)(fmaxf(dot, 0.f) + 0.5f);
    }
}

// ---------------------------------------------------------------------------
// gather: inline per-block scan of dur (wave 0) -> LDS ends; 8 rows/block;
// binary search in LDS; REGULAR stores (L3 write-back — output fits 256MB L3,
// NT stores forced the HBM path). Launched TWICE this round (idempotent) to
// measure gather directly: g_new = total - 36.2 (+ one gap).
// ---------------------------------------------------------------------------
__global__ __launch_bounds__(512) void gather_kernel(
    const float* __restrict__ x, const int* __restrict__ dur,
    float* __restrict__ out)
{
    __shared__ __align__(16) int se[L_];
    const int wid = threadIdx.x >> 6, lane = threadIdx.x & 63;
    const int blk = blockIdx.x;
    const int n = blk >> 9;                 // 512 blocks per batch row

    if (wid == 0) {
        const int* dsrc = dur + n * L_;
        int4 va = reinterpret_cast<const int4*>(dsrc)[lane * 2];
        int4 vb = reinterpret_cast<const int4*>(dsrc)[lane * 2 + 1];
        int p0 = va.x,      p1 = p0 + va.y, p2 = p1 + va.z, p3 = p2 + va.w;
        int p4 = p3 + vb.x, p5 = p4 + vb.y, p6 = p5 + vb.z, p7 = p6 + vb.w;
        int tot = p7;
        #pragma unroll
        for (int m = 1; m < 64; m <<= 1) {
            int tu = __shfl_up(tot, m, 64);
            if (lane >= m) tot += tu;
        }
        int off = tot - p7;
        reinterpret_cast<int4*>(se)[lane * 2]     = make_int4(p0+off, p1+off, p2+off, p3+off);
        reinterpret_cast<int4*>(se)[lane * 2 + 1] = make_int4(p4+off, p5+off, p6+off, p7+off);
    }
    __syncthreads();

    const int t = ((blk & 511) << 3) + wid;
    const int total = se[L_ - 1];

    f32x4 v = {0.f, 0.f, 0.f, 0.f};
    if (t < total) {
        int p = 0;
        #pragma unroll
        for (int step = 256; step > 0; step >>= 1)
            if (p + step <= L_ && se[p + step - 1] <= t) p += step;
        v = reinterpret_cast<const f32x4*>(x + (((size_t)(n * L_ + p)) << 8))[lane];
    }
    reinterpret_cast<f32x4*>(out + (((size_t)(n * T_ + t)) << 8))[lane] = v;
}

// ---------------------------------------------------------------------------
extern "C" void kernel_launch(void* const* d_in, const int* in_sizes, int n_in,
                              void* d_out, int out_size, void* d_ws, size_t ws_size,
                              hipStream_t stream)
{
    const float* x   = (const float*)d_in[0];
    const float* w1  = (const float*)d_in[1];
    const float* b1  = (const float*)d_in[2];
    const float* g1  = (const float*)d_in[3];
    const float* be1 = (const float*)d_in[4];
    const float* w2  = (const float*)d_in[5];
    const float* b2  = (const float*)d_in[6];
    const float* g2  = (const float*)d_in[7];
    const float* be2 = (const float*)d_in[8];
    const float* lw  = (const float*)d_in[9];
    const float* lb  = (const float*)d_in[10];

    float* out = (float*)d_out;
    // fp8 weight-fragment scratch in d_out head (384 KB; gather overwrites)
    unsigned char* bpk1 = (unsigned char*)d_out;
    unsigned char* bpk2 = bpk1 + 196608;
    int* dur = (int*)d_ws;

    pack_w_kernel<<<96, 256, 0, stream>>>(w1, w2, bpk1, bpk2,
                                          out + (size_t)N_ * T_ * C_);

    fused_conv_kernel<<<N_ * (L_ / BM), 512, 0, stream>>>(
        x, bpk1, bpk2, b1, g1, be1, b2, g2, be2, lw, lb, dur);

    // MEASUREMENT: gather launched twice (idempotent — identical output).
    // gather_time = this round's total - 36.2 µs - one dispatch gap.
    gather_kernel<<<N_ * T_ / 8, 512, 0, stream>>>(x, dur, out);
    gather_kernel<<<N_ * T_ / 8, 512, 0, stream>>>(x, dur, out);
}

// Round 19
// 35.055 us; speedup vs baseline: 1.4205x; 1.4205x over previous
//
#include <hip/hip_runtime.h>
#include <math.h>

#define N_   16
#define L_   512
#define C_   256
#define T_   4096
#define EPSL 1e-5f
#define BM   32           // dur rows per block

typedef float f32x4 __attribute__((ext_vector_type(4)));
typedef long  long2v __attribute__((ext_vector_type(2)));

// HW packed fp32 -> fp8 e4m3 (OCP on gfx950): 2 floats -> bytes {lo,hi} of
// one 16-bit half-word of dst; HI selects which half-word (must be literal).
template<bool HI>
__device__ __forceinline__ unsigned cvt2(float a, float b, unsigned old) {
    return (unsigned)__builtin_amdgcn_cvt_pk_fp8_f32(a, b, (int)old, HI);
}

// ---------------------------------------------------------------------------
// pack BOTH conv weights into fp8 MFMA B-fragment-PAIR order + write WVF_pos:
//   bpk[karm][cg(16)][fp(4)][lane(64)][16B] where bytes 0-7 = k-slice s=2fp,
//   bytes 8-15 = s=2fp+1;  byte e of slice s =
//   fp8(w[karm][cin = s*32 + (lane>>4)*8 + e][cout = cg*16 + (lane&15)])
// ---------------------------------------------------------------------------
__global__ __launch_bounds__(256) void pack_w_kernel(
    const float* __restrict__ w1, const float* __restrict__ w2,
    unsigned char* __restrict__ bpk1, unsigned char* __restrict__ bpk2,
    float* __restrict__ wpos)
{
    int gid = blockIdx.x * 256 + threadIdx.x;        // 24576 total (96 blocks)
    if (gid < T_) wpos[gid] = (float)(gid + 1);
    const float* w      = (gid < 12288) ? w1 : w2;
    unsigned char* bpk  = (gid < 12288) ? bpk1 : bpk2;
    int g2 = gid & 12287;
    int lane = g2 & 63;
    int fp   = (g2 >> 6) & 3;
    int cg   = (g2 >> 8) & 15;
    int karm = g2 >> 12;                             // 0..2
    int cout = cg * 16 + (lane & 15);
    int cin0 = (2 * fp) * 32 + (lane >> 4) * 8;      // slice s = 2fp
    const float* s0 = w + (size_t)(karm * 256 + cin0) * 256 + cout;
    const float* s1 = s0 + (size_t)32 * 256;         // slice s = 2fp+1
    float v0[8], v1[8];
    #pragma unroll
    for (int e = 0; e < 8; ++e) {
        v0[e] = s0[(size_t)e * 256];
        v1[e] = s1[(size_t)e * 256];
    }
    unsigned a0 = cvt2<false>(v0[0], v0[1], 0); a0 = cvt2<true>(v0[2], v0[3], a0);
    unsigned a1 = cvt2<false>(v0[4], v0[5], 0); a1 = cvt2<true>(v0[6], v0[7], a1);
    unsigned b0 = cvt2<false>(v1[0], v1[1], 0); b0 = cvt2<true>(v1[2], v1[3], b0);
    unsigned b1 = cvt2<false>(v1[4], v1[5], 0); b1 = cvt2<true>(v1[6], v1[7], b1);
    uint4* dst = reinterpret_cast<uint4*>(bpk + (size_t)g2 * 16);
    *dst = make_uint4(a0, a1, b0, b1);
}

// ---- B prefetch: 2 col-groups x 8 k-slices via 8 dwordx4 loads ----
#define LDB(BPK, KARM, DST) do {                                              \
    const unsigned char* bb_ = (BPK) + ((size_t)((KARM) * 16 + cg0)) * 4096 + lane * 16; \
    _Pragma("unroll")                                                         \
    for (int f_ = 0; f_ < 4; ++f_) {                                          \
        long2v v0_ = *reinterpret_cast<const long2v*>(bb_ + f_ * 1024);       \
        long2v v1_ = *reinterpret_cast<const long2v*>(bb_ + 4096 + f_ * 1024);\
        DST[2*f_]     = v0_[0];  DST[2*f_ + 1]     = v0_[1];                  \
        DST[8 + 2*f_] = v1_[0];  DST[8 + 2*f_ + 1] = v1_[1];                  \
    } } while (0)

// A-fragment LDS byte offset (fp8): row RA, k-slice S, k-group lg.
#define AOFF(BUF, RA, S)                                                      \
    (BUF + (RA) * 256 + (((((S) << 1) + (lg >> 1)) ^ ((RA) & 15)) << 4) + ((lg & 1) << 3))

// ---- one karm of conv1: 3 row-tiles x 2 col-groups = 48 MFMAs ----
#define CONV1K(KARM, B) do {                                                  \
    _Pragma("unroll")                                                         \
    for (int s_ = 0; s_ < 8; ++s_) {                                          \
        _Pragma("unroll")                                                     \
        for (int t_ = 0; t_ < 3; ++t_) {                                      \
            int rA_ = 16 * t_ + lr + (KARM);                                  \
            long a_ = *reinterpret_cast<const long*>(AOFF(xt, rA_, s_));      \
            acc1[t_][0] = __builtin_amdgcn_mfma_f32_16x16x32_fp8_fp8(a_, B[s_],     acc1[t_][0], 0, 0, 0); \
            acc1[t_][1] = __builtin_amdgcn_mfma_f32_16x16x32_fp8_fp8(a_, B[8 + s_], acc1[t_][1], 0, 0, 0); \
        } } } while (0)

// ---- one karm of conv2: 2 row-tiles x 2 col-groups = 32 MFMAs ----
#define CONV2K(KARM, B) do {                                                  \
    _Pragma("unroll")                                                         \
    for (int s_ = 0; s_ < 8; ++s_) {                                          \
        _Pragma("unroll")                                                     \
        for (int t_ = 0; t_ < 2; ++t_) {                                      \
            int rA_ = 16 * t_ + lr + (KARM);                                  \
            long a_ = *reinterpret_cast<const long*>(AOFF(h1t, rA_, s_));     \
            c2[t_][0] = __builtin_amdgcn_mfma_f32_16x16x32_fp8_fp8(a_, B[s_],     c2[t_][0], 0, 0, 0); \
            c2[t_][1] = __builtin_amdgcn_mfma_f32_16x16x32_fp8_fp8(a_, B[8 + s_], c2[t_][1], 0, 0, 0); \
        } } } while (0)

// ---------------------------------------------------------------------------
// FUSED conv1+LN+ReLU -> conv2+LN+ReLU+linear -> dur, fp8 MFMA, HW fp8 cvt.
// Identical to R16 (measured: 12.9 us in graph-replay conditions).
// ---------------------------------------------------------------------------
__global__ __launch_bounds__(512) void fused_conv_kernel(
    const float* __restrict__ x,
    const unsigned char* __restrict__ bpk1, const unsigned char* __restrict__ bpk2,
    const float* __restrict__ b1, const float* __restrict__ g1, const float* __restrict__ be1,
    const float* __restrict__ b2, const float* __restrict__ g2, const float* __restrict__ be2,
    const float* __restrict__ lw, const float* __restrict__ lb,
    int* __restrict__ dur)
{
    __shared__ __align__(16) char xt[50 * 256];      // fp8 rows l0-2 .. (36 staged)
    __shared__ __align__(16) char h1t[34 * 256];     // fp8 h1 rows l0-1 .. l0+32
    __shared__ float redS[8][48], redQ[8][48], redP[8][32];

    const int tid  = threadIdx.x;
    const int wv   = tid >> 6;                       // 0..7
    const int lane = tid & 63;
    const int lg   = lane >> 4;
    const int lr   = lane & 15;
    const int n    = blockIdx.x >> 4;
    const int l0   = (blockIdx.x & 15) << 5;
    const int cg0  = wv * 2;
    const int col0 = wv * 32 + lr, col1 = col0 + 16;

    long Ba[16], Bb[16], Bc[16];
    LDB(bpk1, 0, Ba);                                // in flight during stage
    LDB(bpk1, 1, Bb);

    // ---- stage x rows l0-2 .. l0+33 (36 rows), f32 -> fp8 (HW cvt) ----
    for (int idx = tid; idx < 36 * 16; idx += 512) { // 16B chunk = 16 cols
        int r = idx >> 4, slot = idx & 15;
        int l = l0 - 2 + r;
        unsigned pk[4] = {0, 0, 0, 0};
        if (l >= 0 && l < L_) {
            const float* src = x + (((size_t)(n * L_ + l)) << 8) + (slot << 4);
            #pragma unroll
            for (int q = 0; q < 4; ++q) {
                f32x4 f = *reinterpret_cast<const f32x4*>(src + q * 4);
                unsigned v = cvt2<false>(f[0], f[1], 0);
                pk[q] = cvt2<true>(f[2], f[3], v);
            }
        }
        *reinterpret_cast<uint4*>(xt + r * 256 + ((slot ^ (r & 15)) << 4)) =
            make_uint4(pk[0], pk[1], pk[2], pk[3]);
    }
    __syncthreads();

    // ---- conv1: 2-deep pipelined karm loop ----
    f32x4 acc1[3][2] = {};
    LDB(bpk1, 2, Bc);  CONV1K(0, Ba);
    LDB(bpk2, 0, Ba);  CONV1K(1, Bb);
    LDB(bpk2, 1, Bb);  CONV1K(2, Bc);
    LDB(bpk2, 2, Bc);                                // lands during epilogue

    // ---- conv1 stats: shfl over 16 cols x 2cg, LDS combine over 8 waves ----
    const float cb10 = b1[col0], cb11 = b1[col1];
    const float cg10 = g1[col0], cg11 = g1[col1];
    const float ce10 = be1[col0], ce11 = be1[col1];
    {
        float sv[12], qv[12];
        #pragma unroll
        for (int t = 0; t < 3; ++t)
            #pragma unroll
            for (int j = 0; j < 4; ++j) {
                float h0 = acc1[t][0][j] + cb10, h1 = acc1[t][1][j] + cb11;
                sv[t*4+j] = h0 + h1; qv[t*4+j] = h0 * h0 + h1 * h1;
            }
        #pragma unroll
        for (int m = 1; m < 16; m <<= 1)
            #pragma unroll
            for (int k = 0; k < 12; ++k) {
                sv[k] += __shfl_xor(sv[k], m, 64);
                qv[k] += __shfl_xor(qv[k], m, 64);
            }
        if (lr == 0) {
            #pragma unroll
            for (int t = 0; t < 3; ++t)
                #pragma unroll
                for (int j = 0; j < 4; ++j) {
                    redS[wv][16*t + lg*4 + j] = sv[t*4+j];
                    redQ[wv][16*t + lg*4 + j] = qv[t*4+j];
                }
        }
    }
    __syncthreads();
    if (tid < 48) {
        float ss = 0.f, qq = 0.f;
        #pragma unroll
        for (int u = 0; u < 8; ++u) { ss += redS[u][tid]; qq += redQ[u][tid]; }
        float m_  = ss * (1.f / 256.f);
        float var = fmaxf(qq * (1.f / 256.f) - m_ * m_, 0.f);
        redS[0][tid] = m_;
        redQ[0][tid] = 1.0f / sqrtf(var + EPSL);
    }
    __syncthreads();

    // ---- normalize + ReLU -> h1t fp8 (rows 0..33 kept, HW cvt) ----
    #pragma unroll
    for (int t = 0; t < 3; ++t)
        #pragma unroll
        for (int j = 0; j < 4; ++j) {
            int hr = 16*t + lg*4 + j;
            if (hr < 34) {
                int hl = l0 - 1 + hr;
                float r0 = 0.f, r1 = 0.f;
                if (hl >= 0 && hl < L_) {
                    r0 = fmaxf((acc1[t][0][j] + cb10 - redS[0][hr]) * redQ[0][hr] * cg10 + ce10, 0.f);
                    r1 = fmaxf((acc1[t][1][j] + cb11 - redS[0][hr]) * redQ[0][hr] * cg11 + ce11, 0.f);
                }
                unsigned pr = cvt2<false>(r0, r1, 0);
                *(unsigned char*)(h1t + hr*256 + (((col0 >> 4) ^ (hr & 15)) << 4) + (col0 & 15)) =
                    (unsigned char)(pr & 0xff);
                *(unsigned char*)(h1t + hr*256 + (((col1 >> 4) ^ (hr & 15)) << 4) + (col1 & 15)) =
                    (unsigned char)((pr >> 8) & 0xff);
            }
        }
    __syncthreads();

    // ---- conv2: all three B buffers already resident ----
    f32x4 c2[2][2] = {};
    CONV2K(0, Ba);
    CONV2K(1, Bb);
    CONV2K(2, Bc);

    // ---- conv2 stats ----
    const float cb20 = b2[col0], cb21 = b2[col1];
    const float cg20 = g2[col0], cg21 = g2[col1];
    const float ce20 = be2[col0], ce21 = be2[col1];
    const float lw0  = lw[col0],  lw1  = lw[col1];
    {
        float sv[8], qv[8];
        #pragma unroll
        for (int tt = 0; tt < 2; ++tt)
            #pragma unroll
            for (int j = 0; j < 4; ++j) {
                float h0 = c2[tt][0][j] + cb20, h1 = c2[tt][1][j] + cb21;
                sv[tt*4+j] = h0 + h1; qv[tt*4+j] = h0 * h0 + h1 * h1;
            }
        #pragma unroll
        for (int m = 1; m < 16; m <<= 1)
            #pragma unroll
            for (int k = 0; k < 8; ++k) {
                sv[k] += __shfl_xor(sv[k], m, 64);
                qv[k] += __shfl_xor(qv[k], m, 64);
            }
        if (lr == 0) {
            #pragma unroll
            for (int tt = 0; tt < 2; ++tt)
                #pragma unroll
                for (int j = 0; j < 4; ++j) {
                    redS[wv][16*tt + lg*4 + j] = sv[tt*4+j];
                    redQ[wv][16*tt + lg*4 + j] = qv[tt*4+j];
                }
        }
    }
    __syncthreads();
    if (tid < 32) {
        float ss = 0.f, qq = 0.f;
        #pragma unroll
        for (int u = 0; u < 8; ++u) { ss += redS[u][tid]; qq += redQ[u][tid]; }
        float m_  = ss * (1.f / 256.f);
        float var = fmaxf(qq * (1.f / 256.f) - m_ * m_, 0.f);
        redS[0][tid] = m_;
        redQ[0][tid] = 1.0f / sqrtf(var + EPSL);
    }
    __syncthreads();

    // ---- LN + ReLU + dot(lw) -> dur ----
    {
        float pv[8];
        #pragma unroll
        for (int tt = 0; tt < 2; ++tt)
            #pragma unroll
            for (int j = 0; j < 4; ++j) {
                int r = 16*tt + lg*4 + j;
                float r0 = fmaxf((c2[tt][0][j] + cb20 - redS[0][r]) * redQ[0][r] * cg20 + ce20, 0.f);
                float r1 = fmaxf((c2[tt][1][j] + cb21 - redS[0][r]) * redQ[0][r] * cg21 + ce21, 0.f);
                pv[tt*4+j] = r0 * lw0 + r1 * lw1;
            }
        #pragma unroll
        for (int m = 1; m < 16; m <<= 1)
            #pragma unroll
            for (int k = 0; k < 8; ++k)
                pv[k] += __shfl_xor(pv[k], m, 64);
        if (lr == 0) {
            #pragma unroll
            for (int tt = 0; tt < 2; ++tt)
                #pragma unroll
                for (int j = 0; j < 4; ++j)
                    redP[wv][16*tt + lg*4 + j] = pv[tt*4+j];
        }
    }
    __syncthreads();
    if (tid < 32) {
        float dot = lb[0];
        #pragma unroll
        for (int u = 0; u < 8; ++u) dot += redP[u][tid];
        dur[n * L_ + l0 + tid] = (int)(fmaxf(dot, 0.f) + 0.5f);
    }
}

// ---------------------------------------------------------------------------
// gather: fully wave-independent. Each wave owns one output row: register
// shfl-scan of its batch's dur row (L2-hot, 32KB total) + ballot/popcount
// rank -> source row. No LDS, no barrier, no serial section.
// ---------------------------------------------------------------------------
__global__ __launch_bounds__(512) void gather_kernel(
    const float* __restrict__ x, const int* __restrict__ dur,
    float* __restrict__ out)
{
    const int wid = threadIdx.x >> 6, lane = threadIdx.x & 63;
    const int row = blockIdx.x * 8 + wid;   // row = n*T + t
    const int n = row >> 12;
    const int t = row & (T_ - 1);

    const int4* dsrc = reinterpret_cast<const int4*>(dur + n * L_);
    int4 va = dsrc[lane * 2];
    int4 vb = dsrc[lane * 2 + 1];
    int p0 = va.x,      p1 = p0 + va.y, p2 = p1 + va.z, p3 = p2 + va.w;
    int p4 = p3 + vb.x, p5 = p4 + vb.y, p6 = p5 + vb.z, p7 = p6 + vb.w;
    int tot = p7;
    #pragma unroll
    for (int m = 1; m < 64; m <<= 1) {
        int tu = __shfl_up(tot, m, 64);
        if (lane >= m) tot += tu;
    }
    const int off   = tot - p7;              // exclusive prefix of lane totals
    const int total = __shfl(tot, 63, 64);

    // pos = #{l : ends[l] <= t} via 8 ballots (uniform across the wave)
    int pos = 0;
    pos += __popcll(__ballot(off + p0 <= t));
    pos += __popcll(__ballot(off + p1 <= t));
    pos += __popcll(__ballot(off + p2 <= t));
    pos += __popcll(__ballot(off + p3 <= t));
    pos += __popcll(__ballot(off + p4 <= t));
    pos += __popcll(__ballot(off + p5 <= t));
    pos += __popcll(__ballot(off + p6 <= t));
    pos += __popcll(__ballot(off + p7 <= t));

    f32x4 v = {0.f, 0.f, 0.f, 0.f};
    if (t < total)
        v = reinterpret_cast<const f32x4*>(x + (((size_t)(n * L_ + pos)) << 8))[lane];
    __builtin_nontemporal_store(
        v, reinterpret_cast<f32x4*>(out + ((size_t)row << 8)) + lane);
}

// ---------------------------------------------------------------------------
extern "C" void kernel_launch(void* const* d_in, const int* in_sizes, int n_in,
                              void* d_out, int out_size, void* d_ws, size_t ws_size,
                              hipStream_t stream)
{
    const float* x   = (const float*)d_in[0];
    const float* w1  = (const float*)d_in[1];
    const float* b1  = (const float*)d_in[2];
    const float* g1  = (const float*)d_in[3];
    const float* be1 = (const float*)d_in[4];
    const float* w2  = (const float*)d_in[5];
    const float* b2  = (const float*)d_in[6];
    const float* g2  = (const float*)d_in[7];
    const float* be2 = (const float*)d_in[8];
    const float* lw  = (const float*)d_in[9];
    const float* lb  = (const float*)d_in[10];

    float* out = (float*)d_out;
    // fp8 weight-fragment scratch in d_out head (384 KB; gather overwrites)
    unsigned char* bpk1 = (unsigned char*)d_out;
    unsigned char* bpk2 = bpk1 + 196608;
    int* dur = (int*)d_ws;

    pack_w_kernel<<<96, 256, 0, stream>>>(w1, w2, bpk1, bpk2,
                                          out + (size_t)N_ * T_ * C_);

    fused_conv_kernel<<<N_ * (L_ / BM), 512, 0, stream>>>(
        x, bpk1, bpk2, b1, g1, be1, b2, g2, be2, lw, lb, dur);

    gather_kernel<<<N_ * T_ / 8, 512, 0, stream>>>(x, dur, out);
}